// Round 14
// baseline (378.315 us; speedup 1.0000x reference)
//
#include <hip/hip_runtime.h>
#include <hip/hip_bf16.h>
#include <cstdint>

typedef _Float16 h8 __attribute__((ext_vector_type(8)));
typedef _Float16 h4 __attribute__((ext_vector_type(4)));
typedef float    f4 __attribute__((ext_vector_type(4)));
typedef float    fx16 __attribute__((ext_vector_type(16)));

// Dims: B=16, Cin=256, Ch=128, Br=8, H=W=64, 4096 px/image, 65536 px total.
// ws layout (23 MB):
//   hr   @ 0          16,777,216 B  (f16 [65536 px][128 ch])
//   W1r  @ 16777216    4,718,592 B  (f16 [ci8][tap9][g8][128c][32ch slot-XOR])
//   W2r  @ 21495808      524,288 B  (f16 [g][kc4][256co][32ch])
//   sel1 @ 22020096    2,097,152 B  (f32 [b][g][4096])
//
// LDS involution: 16B slot s at row r lives at slot s ^ ((r>>1)&3).
//
// conv1 (R14) = R6 math/layout with a register-preload phase pipeline:
// 288 chunks of 2 experts (16KB), 4 phases/tap, wt[3] rotating buffers.
// Phase P: buffer(P) = (kx+gp)%3 (ci,ky vanish mod 3 — compile-time in the
// unrolled kx/gp loops); F-register parity = gp&1.
// Ledger: chunk P staged at phase P-2 into buf (P)%3, drained by P-2's end
// barrier (every __syncthreads drains vmcnt), A-frags preloaded to registers
// at P-1, MFMA'd at P. Buffer (P)%3 re-written at P+1... wait: next write to
// that buffer is stage(P+3) at phase P+1 — its last read is the preload at
// phase P-1 -> 2 barriers separation. All cross-accesses >= 1 barrier apart.
// Post-barrier MFMAs issue from registers (no LDS dependency) -> the LDS
// port serves next-phase preloads concurrently with the MFMA burst.

#define GLD16(src, dst) __builtin_amdgcn_global_load_lds( \
    (const __attribute__((address_space(1))) void*)(src), \
    (__attribute__((address_space(3))) void*)(dst), 16, 0, 0)

// ---------------- prep_w: fp32 -> f16 repack, output-major ----------------
__global__ __launch_bounds__(256) void prep_w_k(const float* __restrict__ W1,
        const float* __restrict__ W2, _Float16* __restrict__ W1r,
        _Float16* __restrict__ W2r) {
    int o8 = blockIdx.x * 256 + threadIdx.x;   // one h8 output group per thread
    if (o8 < 294912) {
        int sq = o8 & 3;
        int c  = (o8 >> 2) & 127;
        int g  = (o8 >> 9) & 7;
        int tk = o8 >> 12;                 // cik*9 + tap
        int tap = tk % 9, cik = tk / 9;
        int s = sq ^ ((c >> 1) & 3);
        int ci0 = cik * 32 + s * 8;
        const float* src = W1 + ((size_t)(g * 128 + c) * 256 + ci0) * 9 + tap;
        h8 v;
        #pragma unroll
        for (int e = 0; e < 8; ++e) v[e] = (_Float16)src[e * 9];
        *(h8*)(W1r + (size_t)o8 * 8) = v;
    } else {
        int ow = o8 - 294912;              // W2r h8 groups: 32768
        int sg = ow & 3;
        int co = (ow >> 2) & 255;
        int kc = (ow >> 10) & 3;
        int g  = ow >> 12;
        const float* src = W2 + ((size_t)(g * 256 + co) * 128) + kc * 32 + sg * 8;
        h8 v;
        #pragma unroll
        for (int e = 0; e < 8; ++e) v[e] = (_Float16)src[e];
        *(h8*)(W2r + (size_t)ow * 8) = v;
    }
}

// ---------------- prep_x: sel1 softmax only ----------------
__global__ __launch_bounds__(256) void prep_x_k(const float* __restrict__ x,
        const float* __restrict__ Wc1, const float* __restrict__ bc1,
        float* __restrict__ sel1) {
    __shared__ float wc[2048];            // Wc1 [8][256]
    int t = threadIdx.x;
    for (int i = t; i < 2048; i += 256) wc[i] = Wc1[i];
    __syncthreads();
    int pix = blockIdx.x * 256 + t;       // b*4096 + p
    int b = pix >> 12, p = pix & 4095;
    const float* xp = x + (size_t)b * 1048576 + p;
    float lg[8] = {0.f,0.f,0.f,0.f,0.f,0.f,0.f,0.f};
    for (int c = 0; c < 256; ++c) {
        float v = fmaxf(xp[(size_t)c * 4096], 0.f);
        #pragma unroll
        for (int g = 0; g < 8; ++g) lg[g] += wc[g * 256 + c] * v;
    }
    float m = -1e30f;
    #pragma unroll
    for (int g = 0; g < 8; ++g) { lg[g] += bc1[g]; m = fmaxf(m, lg[g]); }
    float sum = 0.f;
    #pragma unroll
    for (int g = 0; g < 8; ++g) { lg[g] = __expf(lg[g] - m); sum += lg[g]; }
    float inv = 1.f / sum;
    #pragma unroll
    for (int g = 0; g < 8; ++g)
        sel1[(size_t)(b * 8 + g) * 4096 + p] = lg[g] * inv;
}

// ---------------- conv1: switched 3x3, 128c x 256px, register-preload pipe --
#define MFMA_BLOCK(F, GP) do { \
    _Pragma("unroll") \
    for (int gl_ = 0; gl_ < 2; ++gl_) { \
        _Pragma("unroll") \
        for (int kc_ = 0; kc_ < 2; ++kc_) { \
            _Pragma("unroll") \
            for (int nf_ = 0; nf_ < 2; ++nf_) { \
                h8 bs_ = bfr[nf_][kc_] * selv[nf_][(GP) * 2 + gl_]; \
                acc[0][nf_] = __builtin_amdgcn_mfma_f32_32x32x16_f16( \
                    F[gl_ * 4 + kc_ * 2 + 0], bs_, acc[0][nf_], 0, 0, 0); \
                acc[1][nf_] = __builtin_amdgcn_mfma_f32_32x32x16_f16( \
                    F[gl_ * 4 + kc_ * 2 + 1], bs_, acc[1][nf_], 0, 0, 0); \
            } } } \
} while (0)

#define PRELOAD(BI, F) do { \
    const _Float16* wp_ = wt[BI]; \
    _Pragma("unroll") \
    for (int gl_ = 0; gl_ < 2; ++gl_) { \
        _Pragma("unroll") \
        for (int kc_ = 0; kc_ < 2; ++kc_) { \
            _Pragma("unroll") \
            for (int m_ = 0; m_ < 2; ++m_) \
                F[gl_ * 4 + kc_ * 2 + m_] = \
                    *(const h8*)(wp_ + gl_ * 4096 + afo[m_][kc_]); \
        } } \
} while (0)

__global__ __launch_bounds__(512, 2) void conv1_k(const float* __restrict__ x,
        const _Float16* __restrict__ W1r, const float* __restrict__ sel1,
        const float* __restrict__ b1, _Float16* __restrict__ hr) {
    __shared__ _Float16 wt[3][8192];      // 3 x 16KB: [g2][128c][32ch slot-XOR]
    __shared__ _Float16 xs[12296];        // [6 rows][64 col][32 ch slot-XOR] + zero @12288
    int t = threadIdx.x;
    int b = blockIdx.y, yt = blockIdx.x;  // yt: group of 4 output rows
    int y0 = yt * 4;
    int w = t >> 6, l = t & 63;
    int wm = w >> 2, wn = w & 3;          // wm: 64-ch half, wn: output row (64px)
    int l31 = l & 31, kq2 = l >> 5;
    if (t < 8) xs[12288 + t] = (_Float16)0.f;   // zero slot

    fx16 acc[2][2];                       // [m][nf]
    #pragma unroll
    for (int m = 0; m < 2; ++m)
        #pragma unroll
        for (int n = 0; n < 2; ++n)
            #pragma unroll
            for (int e = 0; e < 16; ++e) acc[m][n][e] = 0.f;

    auto stage_w = [&](int P, int bi) {   // one 2-expert chunk (16 KB)
        const _Float16* srcw = W1r + (size_t)P * 8192 + t * 8;
        _Float16* dw = wt[bi] + t * 8;
        GLD16(srcw, dw);
        GLD16(srcw + 4096, dw + 4096);
    };

    // lane constants (R6-identical)
    int px[2];
    #pragma unroll
    for (int nf = 0; nf < 2; ++nf) px[nf] = wn * 64 + nf * 32 + l31;
    bool e0 = (l31 == 0), e63 = (l31 == 31);
    int afo[2][2];
    #pragma unroll
    for (int m = 0; m < 2; ++m)
        #pragma unroll
        for (int kc = 0; kc < 2; ++kc) {
            int c = wm * 64 + m * 32 + l31;
            afo[m][kc] = c * 32 + (((kc * 2 + kq2) ^ ((c >> 1) & 3)) * 8);
        }
    int ba[2][3][2];
    #pragma unroll
    for (int nf = 0; nf < 2; ++nf)
        #pragma unroll
        for (int kx = 0; kx < 3; ++kx) {
            int rz = px[nf] + kx - 1;
            #pragma unroll
            for (int kc = 0; kc < 2; ++kc)
                ba[nf][kx][kc] = rz * 32 + (((kc * 2 + kq2) ^ ((rz >> 1) & 3)) * 8);
        }
    h8 selv[2];
    #pragma unroll
    for (int nf = 0; nf < 2; ++nf)
        #pragma unroll
        for (int g = 0; g < 8; ++g)
            selv[nf][g] = (_Float16)sel1[(size_t)(b * 8 + g) * 4096 + yt * 256 + px[nf]];

    h8 FA[8], FB[8];                      // A-frag double buffer (pure-reg MFMA)
    h8 bfr[2][2];                         // B-frags for current tap [nf][kc]

    // prologue: chunks 0,1 into bufs 0,1; publish; preload chunk 0 -> FA
    stage_w(0, 0);
    stage_w(1, 1);
    __syncthreads();
    PRELOAD(0, FA);

    #pragma unroll 1
    for (int ci = 0; ci < 8; ++ci) {
        // stage relu(x): last xs reader (bfr of ci's last tap) >= 4 barriers ago
        if (t < 384) {
            int r = t >> 6, col = t & 63;
            int rc = r * 64 + col;
            int yi = y0 - 1 + r;
            _Float16* dx = xs + rc * 32;
            int rx = (rc >> 1) & 3;
            if (yi >= 0 && yi < 64) {
                const float* xp = x + ((size_t)(b * 256 + ci * 32)) * 4096 + yi * 64 + col;
                float v[32];
                #pragma unroll
                for (int c2 = 0; c2 < 32; ++c2)
                    v[c2] = fmaxf(xp[(size_t)c2 * 4096], 0.f);
                #pragma unroll
                for (int qq = 0; qq < 4; ++qq) {
                    h8 hv;
                    #pragma unroll
                    for (int e = 0; e < 8; ++e) hv[e] = (_Float16)v[qq * 8 + e];
                    *(h8*)(dx + (qq ^ rx) * 8) = hv;   // involution: read undoes it
                }
            } else {
                const h8 HZ = {};
                #pragma unroll
                for (int qq = 0; qq < 4; ++qq)
                    *(h8*)(dx + (qq ^ rx) * 8) = HZ;
            }
        }
        __syncthreads();                  // publish xs for this ci
        #pragma unroll 1
        for (int ky = 0; ky < 3; ++ky) {
            #pragma unroll
            for (int kx = 0; kx < 3; ++kx) {
                int P0 = (ci * 9 + ky * 3 + kx) * 4;
                // B-frags for this tap (xs stable within ci)
                #pragma unroll
                for (int nf = 0; nf < 2; ++nf)
                    #pragma unroll
                    for (int kc = 0; kc < 2; ++kc) {
                        int a = ba[nf][kx][kc] + ky * 2048;
                        if (kx == 0 && nf == 0) a = e0 ? 12288 : a;
                        if (kx == 2 && nf == 1) a = e63 ? 12288 : a;
                        bfr[nf][kc] = *(const h8*)(xs + a);
                    }
                #pragma unroll
                for (int gp = 0; gp < 4; ++gp) {
                    int P = P0 + gp;
                    if (P < 286) stage_w(P + 2, (kx + gp + 2) % 3);
                    if (gp & 1) {
                        if (P < 287) PRELOAD((kx + gp + 1) % 3, FA);
                        MFMA_BLOCK(FB, gp);
                    } else {
                        if (P < 287) PRELOAD((kx + gp + 1) % 3, FB);
                        MFMA_BLOCK(FA, gp);
                    }
                    __syncthreads();      // drains stage(P+2); publishes for P+1
                }
            }
        }
    }
    // epilogue: + b1, relu, f16, NHWC hr
    // C/D (32x32): col=lane&31, row=(reg&3)+8*(reg>>2)+4*(lane>>5)
    #pragma unroll
    for (int m = 0; m < 2; ++m)
        #pragma unroll
        for (int nf = 0; nf < 2; ++nf) {
            size_t pg = ((size_t)(b * 4096 + yt * 256 + px[nf])) * 128;
            #pragma unroll
            for (int q = 0; q < 4; ++q) {
                int c0 = wm * 64 + m * 32 + q * 8 + kq2 * 4;
                f4 bb = *(const f4*)(b1 + c0);
                h4 hv;
                #pragma unroll
                for (int r = 0; r < 4; ++r)
                    hv[r] = (_Float16)fmaxf(acc[m][nf][q * 4 + r] + bb[r], 0.f);
                *(h4*)(hr + pg + c0) = hv;
            }
        }
}

// ---------------- conv2: switched 1x1 + fused sel2 softmax + residual ------
__global__ __launch_bounds__(256, 2) void conv2_k(const _Float16* __restrict__ hr,
        const _Float16* __restrict__ W2r, const float* __restrict__ Wc2,
        const float* __restrict__ bc2, const float* __restrict__ b2,
        const float* __restrict__ x, float* __restrict__ out) {
    __shared__ _Float16 hs[64 * 128];        // [64 px][128 ch] swizzled (16KB)
    __shared__ _Float16 wt[2][256 * 32];     // dbuf [256 co][32 ch] swizzled (32KB)
    __shared__ float wc[1024];               // Wc2 [8][128] (4KB)
    __shared__ float red[2048];              // [64 px][8 g][4 strip] (8KB)
    __shared__ float selw[512];              // [64 px][8 g] (2KB)
    int t = threadIdx.x;
    int bid = blockIdx.x;
    int b = bid >> 6, p0 = (bid & 63) * 64;
    int l = t & 63, w = t >> 6;
    int wm = w >> 1, wn = w & 1;
    int l15 = l & 15, sl = l >> 4;
    int swl = (l15 & 7) << 3;
    const f4 FZ = {0.f, 0.f, 0.f, 0.f};
    f4 acce[8][2], accf[8][2];
    #pragma unroll
    for (int m = 0; m < 8; ++m)
        #pragma unroll
        for (int n = 0; n < 2; ++n) { acce[m][n] = FZ; accf[m][n] = FZ; }
    for (int i = t; i < 1024; i += 256) wc[i] = Wc2[i];
    {   // stage h tile (swizzled)
        int px = t >> 2, qq = t & 3;
        const _Float16* src = hr + (size_t)(b * 4096 + p0 + px) * 128 + qq * 32;
        #pragma unroll
        for (int u = 0; u < 4; ++u)
            *(h8*)(hs + ((px * 128 + qq * 32 + u * 8) ^ ((px & 7) << 3)))
                = *(const h8*)(src + u * 8);
    }
    h8 wr[4];
    auto load_w = [&](int T) {
        const _Float16* srcw = W2r + (size_t)T * 8192;
        #pragma unroll
        for (int it = 0; it < 4; ++it)
            wr[it] = *(const h8*)(srcw + (size_t)(it * 256 + t) * 8);
    };
    auto write_w = [&](int bf) {
        #pragma unroll
        for (int it = 0; it < 4; ++it) {
            int cc = it * 256 + t;
            int c = cc >> 2, q = cc & 3;
            *(h8*)(wt[bf] + ((c * 32 + q * 8) ^ ((c & 7) << 3))) = wr[it];
        }
    };
    load_w(0);
    __syncthreads();                      // publish hs + wc
    {   // fused sel2: partial logits (4 threads/px x 32 ch)
        int px = t >> 2, qq = t & 3;
        float lg[8] = {0.f,0.f,0.f,0.f,0.f,0.f,0.f,0.f};
        #pragma unroll
        for (int u = 0; u < 4; ++u) {
            h8 v = *(const h8*)(hs + ((px * 128 + qq * 32 + u * 8) ^ ((px & 7) << 3)));
            #pragma unroll
            for (int e = 0; e < 8; ++e) {
                float f = (float)v[e];
                int c = qq * 32 + u * 8 + e;
                #pragma unroll
                for (int g = 0; g < 8; ++g) lg[g] += wc[g * 128 + c] * f;
            }
        }
        #pragma unroll
        for (int g = 0; g < 8; ++g) red[(px * 8 + g) * 4 + qq] = lg[g];
    }
    __syncthreads();
    if (t < 64) {                         // softmax per pixel
        float lg[8]; float m = -1e30f;
        #pragma unroll
        for (int g = 0; g < 8; ++g) {
            lg[g] = red[(t*8+g)*4+0] + red[(t*8+g)*4+1]
                  + red[(t*8+g)*4+2] + red[(t*8+g)*4+3] + bc2[g];
            m = fmaxf(m, lg[g]);
        }
        float sum = 0.f;
        #pragma unroll
        for (int g = 0; g < 8; ++g) { lg[g] = __expf(lg[g] - m); sum += lg[g]; }
        float inv = 1.f / sum;
        #pragma unroll
        for (int g = 0; g < 8; ++g) selw[t * 8 + g] = lg[g] * inv;
    }
    write_w(0);                           // wt[0] LDS writes (no reader yet)
    __syncthreads();                      // publish selw + wt[0]
    float selr[8][2];
    #pragma unroll
    for (int g = 0; g < 8; ++g)
        #pragma unroll
        for (int n = 0; n < 2; ++n)
            selr[g][n] = selw[(wn * 32 + n * 16 + l15) * 8 + g];
    int afo[8];
    #pragma unroll
    for (int m = 0; m < 8; ++m) {
        int c = wm * 128 + m * 16 + l15;
        afo[m] = ((c * 32 + sl * 8) ^ swl);
    }
    int buf = 0;
    #pragma unroll 1
    for (int T = 0; T < 32; ++T) {          // T = g*4 + kchunk
        bool hn = (T < 31);
        if (hn) load_w(T + 1);
        __syncthreads();   // publishes wt[buf]
        int kc = (T & 3) * 32;
        h8 bfv[2];
        #pragma unroll
        for (int n = 0; n < 2; ++n) {
            int px = wn * 32 + n * 16 + l15;
            bfv[n] = *(const h8*)(hs + ((px * 128 + kc + sl * 8) ^ ((px & 7) << 3)));
        }
        #pragma unroll
        for (int m = 0; m < 8; ++m) {
            h8 af = *(const h8*)(wt[buf] + afo[m]);
            #pragma unroll
            for (int n = 0; n < 2; ++n)
                acce[m][n] = __builtin_amdgcn_mfma_f32_16x16x32_f16(
                    af, bfv[n], acce[m][n], 0, 0, 0);
        }
        if ((T & 3) == 3) {
            int g = T >> 2;
            #pragma unroll
            for (int n = 0; n < 2; ++n)
                #pragma unroll
                for (int m = 0; m < 8; ++m) {
                    accf[m][n] += selr[g][n] * acce[m][n];
                    acce[m][n] = FZ;
                }
        }
        if (hn) write_w(buf ^ 1);
        buf ^= 1;
    }
    // epilogue: + b2 + residual x, fp32 NCHW out
    #pragma unroll
    for (int m = 0; m < 8; ++m) {
        int c0 = wm * 128 + m * 16 + sl * 4;
        f4 bb = *(const f4*)(b2 + c0);
        #pragma unroll
        for (int n = 0; n < 2; ++n) {
            int px = wn * 32 + n * 16 + l15;
            size_t o = (size_t)(b * 256 + c0) * 4096 + p0 + px;
            #pragma unroll
            for (int r = 0; r < 4; ++r)
                out[o + (size_t)r * 4096] = accf[m][n][r] + bb[r] + x[o + (size_t)r * 4096];
        }
    }
}

extern "C" void kernel_launch(void* const* d_in, const int* in_sizes, int n_in,
                              void* d_out, int out_size, void* d_ws, size_t ws_size,
                              hipStream_t stream) {
    const float* x   = (const float*)d_in[0];
    const float* W1  = (const float*)d_in[1];
    const float* b1  = (const float*)d_in[2];
    const float* Wc1 = (const float*)d_in[3];
    const float* bc1 = (const float*)d_in[4];
    const float* W2  = (const float*)d_in[5];
    const float* b2  = (const float*)d_in[6];
    const float* Wc2 = (const float*)d_in[7];
    const float* bc2 = (const float*)d_in[8];
    float* out = (float*)d_out;
    char* ws = (char*)d_ws;
    _Float16* hr  = (_Float16*)(ws);                   // 16,777,216 B
    _Float16* W1r = (_Float16*)(ws + 16777216);        //  4,718,592 B
    _Float16* W2r = (_Float16*)(ws + 21495808);        //    524,288 B
    float* sel1   = (float*)(ws + 22020096);           //  2,097,152 B

    hipLaunchKernelGGL(prep_w_k, dim3(1280), dim3(256), 0, stream, W1, W2, W1r, W2r);
    hipLaunchKernelGGL(prep_x_k, dim3(256), dim3(256), 0, stream, x, Wc1, bc1, sel1);
    hipLaunchKernelGGL(conv1_k, dim3(16, 16), dim3(512), 0, stream, x, W1r, sel1, b1, hr);
    hipLaunchKernelGGL(conv2_k, dim3(1024), dim3(256), 0, stream, hr, W2r, Wc2, bc2, b2, x, out);
}

// Round 15
// 337.688 us; speedup vs baseline: 1.1203x; 1.1203x over previous
//
#include <hip/hip_runtime.h>
#include <hip/hip_bf16.h>
#include <cstdint>

typedef _Float16 h8 __attribute__((ext_vector_type(8)));
typedef _Float16 h4 __attribute__((ext_vector_type(4)));
typedef float    f4 __attribute__((ext_vector_type(4)));
typedef float    fx16 __attribute__((ext_vector_type(16)));

// Dims: B=16, Cin=256, Ch=128, Br=8, H=W=64, 4096 px/image, 65536 px total.
// ws layout (23 MB):
//   hr   @ 0          16,777,216 B  (f16 [65536 px][128 ch])
//   W1r  @ 16777216    4,718,592 B  (f16 [ci8][tap9][g8][128c][32ch slot-XOR])
//   W2r  @ 21495808      524,288 B  (f16 [g][kc4][256co][32ch])
//   sel1 @ 22020096    2,097,152 B  (f32 [b][g][4096])
//
// LDS involution: 16B slot s at row r lives at slot s ^ ((r>>1)&3).
//
// conv1 (R15) = R14's verified 16KB-chunk / wt[3]-rotation structure with
// T4 counted-vmcnt sync (m218: counted-vs-drain0 = +38-73%):
//   per phase P: s_barrier ; s_waitcnt vmcnt(2) ; sched_barrier(0) ;
//                ds_read A-frags from wt[(kx+gp)%3] ; 16 MFMA ;
//                stage_w(P+2 -> (kx+gp+2)%3)   [2 GLD16, stays in flight]
// vmcnt ledger: stage(P) issued end of P-2, stage(P+1) end of P-1 -> at top
// of P outstanding<=4; vmcnt(2) retires the OLDEST 2 = stage(P) (m135).
// Race ledger: buf rewritten by stage(P+2) was last read at phase P-1; the
// top-of-P s_barrier separates (reads consumed into regs pre-barrier).
// vmcnt(0) on the last 2 phases (nothing left in flight to count against).
// __syncthreads only at ci boundary (xs ds_write publication needs lgkm drain).

#define GLD16(src, dst) __builtin_amdgcn_global_load_lds( \
    (const __attribute__((address_space(1))) void*)(src), \
    (__attribute__((address_space(3))) void*)(dst), 16, 0, 0)

// ---------------- prep_w: fp32 -> f16 repack, output-major ----------------
__global__ __launch_bounds__(256) void prep_w_k(const float* __restrict__ W1,
        const float* __restrict__ W2, _Float16* __restrict__ W1r,
        _Float16* __restrict__ W2r) {
    int o8 = blockIdx.x * 256 + threadIdx.x;   // one h8 output group per thread
    if (o8 < 294912) {
        int sq = o8 & 3;
        int c  = (o8 >> 2) & 127;
        int g  = (o8 >> 9) & 7;
        int tk = o8 >> 12;                 // cik*9 + tap
        int tap = tk % 9, cik = tk / 9;
        int s = sq ^ ((c >> 1) & 3);
        int ci0 = cik * 32 + s * 8;
        const float* src = W1 + ((size_t)(g * 128 + c) * 256 + ci0) * 9 + tap;
        h8 v;
        #pragma unroll
        for (int e = 0; e < 8; ++e) v[e] = (_Float16)src[e * 9];
        *(h8*)(W1r + (size_t)o8 * 8) = v;
    } else {
        int ow = o8 - 294912;              // W2r h8 groups: 32768
        int sg = ow & 3;
        int co = (ow >> 2) & 255;
        int kc = (ow >> 10) & 3;
        int g  = ow >> 12;
        const float* src = W2 + ((size_t)(g * 256 + co) * 128) + kc * 32 + sg * 8;
        h8 v;
        #pragma unroll
        for (int e = 0; e < 8; ++e) v[e] = (_Float16)src[e];
        *(h8*)(W2r + (size_t)ow * 8) = v;
    }
}

// ---------------- prep_x: sel1 softmax only ----------------
__global__ __launch_bounds__(256) void prep_x_k(const float* __restrict__ x,
        const float* __restrict__ Wc1, const float* __restrict__ bc1,
        float* __restrict__ sel1) {
    __shared__ float wc[2048];            // Wc1 [8][256]
    int t = threadIdx.x;
    for (int i = t; i < 2048; i += 256) wc[i] = Wc1[i];
    __syncthreads();
    int pix = blockIdx.x * 256 + t;       // b*4096 + p
    int b = pix >> 12, p = pix & 4095;
    const float* xp = x + (size_t)b * 1048576 + p;
    float lg[8] = {0.f,0.f,0.f,0.f,0.f,0.f,0.f,0.f};
    for (int c = 0; c < 256; ++c) {
        float v = fmaxf(xp[(size_t)c * 4096], 0.f);
        #pragma unroll
        for (int g = 0; g < 8; ++g) lg[g] += wc[g * 256 + c] * v;
    }
    float m = -1e30f;
    #pragma unroll
    for (int g = 0; g < 8; ++g) { lg[g] += bc1[g]; m = fmaxf(m, lg[g]); }
    float sum = 0.f;
    #pragma unroll
    for (int g = 0; g < 8; ++g) { lg[g] = __expf(lg[g] - m); sum += lg[g]; }
    float inv = 1.f / sum;
    #pragma unroll
    for (int g = 0; g < 8; ++g)
        sel1[(size_t)(b * 8 + g) * 4096 + p] = lg[g] * inv;
}

// ---------------- conv1: switched 3x3, 128c x 256px, counted-vmcnt pipe ----
__global__ __launch_bounds__(512, 2) void conv1_k(const float* __restrict__ x,
        const _Float16* __restrict__ W1r, const float* __restrict__ sel1,
        const float* __restrict__ b1, _Float16* __restrict__ hr) {
    __shared__ _Float16 wt[3][8192];      // 3 x 16KB: [g2][128c][32ch slot-XOR]
    __shared__ _Float16 xs[12296];        // [6 rows][64 col][32 ch slot-XOR] + zero @12288
    int t = threadIdx.x;
    int b = blockIdx.y, yt = blockIdx.x;  // yt: group of 4 output rows
    int y0 = yt * 4;
    int w = t >> 6, l = t & 63;
    int wm = w >> 2, wn = w & 3;          // wm: 64-ch half, wn: output row (64px)
    int l31 = l & 31, kq2 = l >> 5;
    if (t < 8) xs[12288 + t] = (_Float16)0.f;   // zero slot

    fx16 acc[2][2];                       // [m][nf]
    #pragma unroll
    for (int m = 0; m < 2; ++m)
        #pragma unroll
        for (int n = 0; n < 2; ++n)
            #pragma unroll
            for (int e = 0; e < 16; ++e) acc[m][n][e] = 0.f;

    auto stage_w = [&](int P, int bi) {   // one 2-expert chunk (16 KB)
        const _Float16* srcw = W1r + (size_t)P * 8192 + t * 8;
        _Float16* dw = wt[bi] + t * 8;
        GLD16(srcw, dw);
        GLD16(srcw + 4096, dw + 4096);
    };

    // lane constants (R6-identical)
    int px[2];
    #pragma unroll
    for (int nf = 0; nf < 2; ++nf) px[nf] = wn * 64 + nf * 32 + l31;
    bool e0 = (l31 == 0), e63 = (l31 == 31);
    int afo[2][2];
    #pragma unroll
    for (int m = 0; m < 2; ++m)
        #pragma unroll
        for (int kc = 0; kc < 2; ++kc) {
            int c = wm * 64 + m * 32 + l31;
            afo[m][kc] = c * 32 + (((kc * 2 + kq2) ^ ((c >> 1) & 3)) * 8);
        }
    int ba[2][3][2];
    #pragma unroll
    for (int nf = 0; nf < 2; ++nf)
        #pragma unroll
        for (int kx = 0; kx < 3; ++kx) {
            int rz = px[nf] + kx - 1;
            #pragma unroll
            for (int kc = 0; kc < 2; ++kc)
                ba[nf][kx][kc] = rz * 32 + (((kc * 2 + kq2) ^ ((rz >> 1) & 3)) * 8);
        }
    h8 selv[2];
    #pragma unroll
    for (int nf = 0; nf < 2; ++nf)
        #pragma unroll
        for (int g = 0; g < 8; ++g)
            selv[nf][g] = (_Float16)sel1[(size_t)(b * 8 + g) * 4096 + yt * 256 + px[nf]];

    h8 bfr[2][2];                         // B-frags for current tap [nf][kc]

    // prologue: chunks 0,1 into bufs 0,1 (in flight)
    stage_w(0, 0);
    stage_w(1, 1);

    #pragma unroll 1
    for (int ci = 0; ci < 8; ++ci) {
        // stage relu(x): previous xs readers all completed >= 1 phase-barrier ago
        if (t < 384) {
            int r = t >> 6, col = t & 63;
            int rc = r * 64 + col;
            int yi = y0 - 1 + r;
            _Float16* dx = xs + rc * 32;
            int rx = (rc >> 1) & 3;
            if (yi >= 0 && yi < 64) {
                const float* xp = x + ((size_t)(b * 256 + ci * 32)) * 4096 + yi * 64 + col;
                float v[32];
                #pragma unroll
                for (int c2 = 0; c2 < 32; ++c2)
                    v[c2] = fmaxf(xp[(size_t)c2 * 4096], 0.f);
                #pragma unroll
                for (int qq = 0; qq < 4; ++qq) {
                    h8 hv;
                    #pragma unroll
                    for (int e = 0; e < 8; ++e) hv[e] = (_Float16)v[qq * 8 + e];
                    *(h8*)(dx + (qq ^ rx) * 8) = hv;   // involution: read undoes it
                }
            } else {
                const h8 HZ = {};
                #pragma unroll
                for (int qq = 0; qq < 4; ++qq)
                    *(h8*)(dx + (qq ^ rx) * 8) = HZ;
            }
        }
        __syncthreads();                  // publish xs (full drain, 1x per ci)
        #pragma unroll 1
        for (int ky = 0; ky < 3; ++ky) {
            #pragma unroll
            for (int kx = 0; kx < 3; ++kx) {
                int P0 = (ci * 9 + ky * 3 + kx) * 4;
                // B-frags for this tap (xs stable within ci)
                #pragma unroll
                for (int nf = 0; nf < 2; ++nf)
                    #pragma unroll
                    for (int kc = 0; kc < 2; ++kc) {
                        int a = ba[nf][kx][kc] + ky * 2048;
                        if (kx == 0 && nf == 0) a = e0 ? 12288 : a;
                        if (kx == 2 && nf == 1) a = e63 ? 12288 : a;
                        bfr[nf][kc] = *(const h8*)(xs + a);
                    }
                #pragma unroll
                for (int gp = 0; gp < 4; ++gp) {
                    int P = P0 + gp;
                    __builtin_amdgcn_s_barrier();      // raw barrier, no drain
                    if (P >= 286) {                    // tail: nothing behind
                        asm volatile("s_waitcnt vmcnt(0)" ::: "memory");
                    } else {                           // counted: stage(P) only
                        asm volatile("s_waitcnt vmcnt(2)" ::: "memory");
                    }
                    __builtin_amdgcn_sched_barrier(0);
                    const _Float16* wp = wt[(kx + gp) % 3];
                    #pragma unroll
                    for (int gl = 0; gl < 2; ++gl) {
                        #pragma unroll
                        for (int kc = 0; kc < 2; ++kc) {
                            h8 a0 = *(const h8*)(wp + gl * 4096 + afo[0][kc]);
                            h8 a1 = *(const h8*)(wp + gl * 4096 + afo[1][kc]);
                            #pragma unroll
                            for (int nf = 0; nf < 2; ++nf) {
                                h8 bs = bfr[nf][kc] * selv[nf][gp * 2 + gl];
                                acc[0][nf] = __builtin_amdgcn_mfma_f32_32x32x16_f16(
                                    a0, bs, acc[0][nf], 0, 0, 0);
                                acc[1][nf] = __builtin_amdgcn_mfma_f32_32x32x16_f16(
                                    a1, bs, acc[1][nf], 0, 0, 0);
                            }
                        }
                    }
                    if (P < 286) stage_w(P + 2, (kx + gp + 2) % 3);
                }
            }
        }
    }
    // epilogue: + b1, relu, f16, NHWC hr
    // C/D (32x32): col=lane&31, row=(reg&3)+8*(reg>>2)+4*(lane>>5)
    #pragma unroll
    for (int m = 0; m < 2; ++m)
        #pragma unroll
        for (int nf = 0; nf < 2; ++nf) {
            size_t pg = ((size_t)(b * 4096 + yt * 256 + px[nf])) * 128;
            #pragma unroll
            for (int q = 0; q < 4; ++q) {
                int c0 = wm * 64 + m * 32 + q * 8 + kq2 * 4;
                f4 bb = *(const f4*)(b1 + c0);
                h4 hv;
                #pragma unroll
                for (int r = 0; r < 4; ++r)
                    hv[r] = (_Float16)fmaxf(acc[m][nf][q * 4 + r] + bb[r], 0.f);
                *(h4*)(hr + pg + c0) = hv;
            }
        }
}

// ---------------- conv2: switched 1x1 + fused sel2 softmax + residual ------
__global__ __launch_bounds__(256, 2) void conv2_k(const _Float16* __restrict__ hr,
        const _Float16* __restrict__ W2r, const float* __restrict__ Wc2,
        const float* __restrict__ bc2, const float* __restrict__ b2,
        const float* __restrict__ x, float* __restrict__ out) {
    __shared__ _Float16 hs[64 * 128];        // [64 px][128 ch] swizzled (16KB)
    __shared__ _Float16 wt[2][256 * 32];     // dbuf [256 co][32 ch] swizzled (32KB)
    __shared__ float wc[1024];               // Wc2 [8][128] (4KB)
    __shared__ float red[2048];              // [64 px][8 g][4 strip] (8KB)
    __shared__ float selw[512];              // [64 px][8 g] (2KB)
    int t = threadIdx.x;
    int bid = blockIdx.x;
    int b = bid >> 6, p0 = (bid & 63) * 64;
    int l = t & 63, w = t >> 6;
    int wm = w >> 1, wn = w & 1;
    int l15 = l & 15, sl = l >> 4;
    int swl = (l15 & 7) << 3;
    const f4 FZ = {0.f, 0.f, 0.f, 0.f};
    f4 acce[8][2], accf[8][2];
    #pragma unroll
    for (int m = 0; m < 8; ++m)
        #pragma unroll
        for (int n = 0; n < 2; ++n) { acce[m][n] = FZ; accf[m][n] = FZ; }
    for (int i = t; i < 1024; i += 256) wc[i] = Wc2[i];
    {   // stage h tile (swizzled)
        int px = t >> 2, qq = t & 3;
        const _Float16* src = hr + (size_t)(b * 4096 + p0 + px) * 128 + qq * 32;
        #pragma unroll
        for (int u = 0; u < 4; ++u)
            *(h8*)(hs + ((px * 128 + qq * 32 + u * 8) ^ ((px & 7) << 3)))
                = *(const h8*)(src + u * 8);
    }
    h8 wr[4];
    auto load_w = [&](int T) {
        const _Float16* srcw = W2r + (size_t)T * 8192;
        #pragma unroll
        for (int it = 0; it < 4; ++it)
            wr[it] = *(const h8*)(srcw + (size_t)(it * 256 + t) * 8);
    };
    auto write_w = [&](int bf) {
        #pragma unroll
        for (int it = 0; it < 4; ++it) {
            int cc = it * 256 + t;
            int c = cc >> 2, q = cc & 3;
            *(h8*)(wt[bf] + ((c * 32 + q * 8) ^ ((c & 7) << 3))) = wr[it];
        }
    };
    load_w(0);
    __syncthreads();                      // publish hs + wc
    {   // fused sel2: partial logits (4 threads/px x 32 ch)
        int px = t >> 2, qq = t & 3;
        float lg[8] = {0.f,0.f,0.f,0.f,0.f,0.f,0.f,0.f};
        #pragma unroll
        for (int u = 0; u < 4; ++u) {
            h8 v = *(const h8*)(hs + ((px * 128 + qq * 32 + u * 8) ^ ((px & 7) << 3)));
            #pragma unroll
            for (int e = 0; e < 8; ++e) {
                float f = (float)v[e];
                int c = qq * 32 + u * 8 + e;
                #pragma unroll
                for (int g = 0; g < 8; ++g) lg[g] += wc[g * 128 + c] * f;
            }
        }
        #pragma unroll
        for (int g = 0; g < 8; ++g) red[(px * 8 + g) * 4 + qq] = lg[g];
    }
    __syncthreads();
    if (t < 64) {                         // softmax per pixel
        float lg[8]; float m = -1e30f;
        #pragma unroll
        for (int g = 0; g < 8; ++g) {
            lg[g] = red[(t*8+g)*4+0] + red[(t*8+g)*4+1]
                  + red[(t*8+g)*4+2] + red[(t*8+g)*4+3] + bc2[g];
            m = fmaxf(m, lg[g]);
        }
        float sum = 0.f;
        #pragma unroll
        for (int g = 0; g < 8; ++g) { lg[g] = __expf(lg[g] - m); sum += lg[g]; }
        float inv = 1.f / sum;
        #pragma unroll
        for (int g = 0; g < 8; ++g) selw[t * 8 + g] = lg[g] * inv;
    }
    write_w(0);                           // wt[0] LDS writes (no reader yet)
    __syncthreads();                      // publish selw + wt[0]
    float selr[8][2];
    #pragma unroll
    for (int g = 0; g < 8; ++g)
        #pragma unroll
        for (int n = 0; n < 2; ++n)
            selr[g][n] = selw[(wn * 32 + n * 16 + l15) * 8 + g];
    int afo[8];
    #pragma unroll
    for (int m = 0; m < 8; ++m) {
        int c = wm * 128 + m * 16 + l15;
        afo[m] = ((c * 32 + sl * 8) ^ swl);
    }
    int buf = 0;
    #pragma unroll 1
    for (int T = 0; T < 32; ++T) {          // T = g*4 + kchunk
        bool hn = (T < 31);
        if (hn) load_w(T + 1);
        __syncthreads();   // publishes wt[buf]
        int kc = (T & 3) * 32;
        h8 bfv[2];
        #pragma unroll
        for (int n = 0; n < 2; ++n) {
            int px = wn * 32 + n * 16 + l15;
            bfv[n] = *(const h8*)(hs + ((px * 128 + kc + sl * 8) ^ ((px & 7) << 3)));
        }
        #pragma unroll
        for (int m = 0; m < 8; ++m) {
            h8 af = *(const h8*)(wt[buf] + afo[m]);
            #pragma unroll
            for (int n = 0; n < 2; ++n)
                acce[m][n] = __builtin_amdgcn_mfma_f32_16x16x32_f16(
                    af, bfv[n], acce[m][n], 0, 0, 0);
        }
        if ((T & 3) == 3) {
            int g = T >> 2;
            #pragma unroll
            for (int n = 0; n < 2; ++n)
                #pragma unroll
                for (int m = 0; m < 8; ++m) {
                    accf[m][n] += selr[g][n] * acce[m][n];
                    acce[m][n] = FZ;
                }
        }
        if (hn) write_w(buf ^ 1);
        buf ^= 1;
    }
    // epilogue: + b2 + residual x, fp32 NCHW out
    #pragma unroll
    for (int m = 0; m < 8; ++m) {
        int c0 = wm * 128 + m * 16 + sl * 4;
        f4 bb = *(const f4*)(b2 + c0);
        #pragma unroll
        for (int n = 0; n < 2; ++n) {
            int px = wn * 32 + n * 16 + l15;
            size_t o = (size_t)(b * 256 + c0) * 4096 + p0 + px;
            #pragma unroll
            for (int r = 0; r < 4; ++r)
                out[o + (size_t)r * 4096] = accf[m][n][r] + bb[r] + x[o + (size_t)r * 4096];
        }
    }
}

extern "C" void kernel_launch(void* const* d_in, const int* in_sizes, int n_in,
                              void* d_out, int out_size, void* d_ws, size_t ws_size,
                              hipStream_t stream) {
    const float* x   = (const float*)d_in[0];
    const float* W1  = (const float*)d_in[1];
    const float* b1  = (const float*)d_in[2];
    const float* Wc1 = (const float*)d_in[3];
    const float* bc1 = (const float*)d_in[4];
    const float* W2  = (const float*)d_in[5];
    const float* b2  = (const float*)d_in[6];
    const float* Wc2 = (const float*)d_in[7];
    const float* bc2 = (const float*)d_in[8];
    float* out = (float*)d_out;
    char* ws = (char*)d_ws;
    _Float16* hr  = (_Float16*)(ws);                   // 16,777,216 B
    _Float16* W1r = (_Float16*)(ws + 16777216);        //  4,718,592 B
    _Float16* W2r = (_Float16*)(ws + 21495808);        //    524,288 B
    float* sel1   = (float*)(ws + 22020096);           //  2,097,152 B

    hipLaunchKernelGGL(prep_w_k, dim3(1280), dim3(256), 0, stream, W1, W2, W1r, W2r);
    hipLaunchKernelGGL(prep_x_k, dim3(256), dim3(256), 0, stream, x, Wc1, bc1, sel1);
    hipLaunchKernelGGL(conv1_k, dim3(16, 16), dim3(512), 0, stream, x, W1r, sel1, b1, hr);
    hipLaunchKernelGGL(conv2_k, dim3(1024), dim3(256), 0, stream, hr, W2r, Wc2, bc2, b2, x, out);
}